// Round 1
// baseline (517.133 us; speedup 1.0000x reference)
//
#include <hip/hip_runtime.h>
#include <math.h>

#define K 8
#define D 256
#define NSLOTS 32
#define NB 2048
#define BT 256
#define F_EPS 1e-12f
#define MOM 0.9f

__device__ __forceinline__ float wave_allreduce_add(float v) {
#pragma unroll
    for (int m = 1; m < 64; m <<= 1) v += __shfl_xor(v, m, 64);
    return v;
}

// Pass 1: normalize rows, argmax vs prototypes, segment-sum normalized rows.
__global__ __launch_bounds__(BT) void k_source(const float* __restrict__ src,
                                               const float* __restrict__ protos,
                                               float* __restrict__ ws_sums,   // [NSLOTS][K][D]
                                               float* __restrict__ ws_cnts,   // [NSLOTS][K]
                                               int nrows) {
    __shared__ float lsums[K][4][64];   // [cluster][j][lane] -> element 4*lane+j ; lane stride 4B => conflict-free
    __shared__ float lcounts[K];
    const int tid = threadIdx.x;
    for (int i = tid; i < K * 4 * 64; i += BT) ((float*)lsums)[i] = 0.0f;
    if (tid < K) lcounts[tid] = 0.0f;
    __syncthreads();

    const int lane = tid & 63;
    const int gwave = (blockIdx.x * BT + tid) >> 6;
    const int nwaves = gridDim.x * (BT / 64);

    float4 p[K];
#pragma unroll
    for (int k = 0; k < K; ++k)
        p[k] = *(const float4*)(protos + k * D + 4 * lane);

    for (int row = gwave; row < nrows; row += nwaves) {
        float4 v = *(const float4*)(src + (size_t)row * D + 4 * lane);
        float nrm = v.x * v.x + v.y * v.y + v.z * v.z + v.w * v.w;
        float dot[K];
#pragma unroll
        for (int k = 0; k < K; ++k)
            dot[k] = v.x * p[k].x + v.y * p[k].y + v.z * p[k].z + v.w * p[k].w;
#pragma unroll
        for (int m = 1; m < 64; m <<= 1) {
            nrm += __shfl_xor(nrm, m, 64);
#pragma unroll
            for (int k = 0; k < K; ++k) dot[k] += __shfl_xor(dot[k], m, 64);
        }
        float inv = 1.0f / fmaxf(sqrtf(nrm), F_EPS);
        // argmax (scale by inv>0 doesn't change it); first-max semantics via strict >
        int best = 0;
        float bv = dot[0];
#pragma unroll
        for (int k = 1; k < K; ++k)
            if (dot[k] > bv) { bv = dot[k]; best = k; }
        atomicAdd(&lsums[best][0][lane], v.x * inv);
        atomicAdd(&lsums[best][1][lane], v.y * inv);
        atomicAdd(&lsums[best][2][lane], v.z * inv);
        atomicAdd(&lsums[best][3][lane], v.w * inv);
        if (lane == 0) atomicAdd(&lcounts[best], 1.0f);
    }
    __syncthreads();

    const int slot = blockIdx.x & (NSLOTS - 1);
    float* gs = ws_sums + (size_t)slot * (K * D);
    for (int i = tid; i < K * D; i += BT) {
        int k = i >> 8;
        int e = i & 255;
        unsafeAtomicAdd(&gs[i], lsums[k][e & 3][e >> 2]);
    }
    if (tid < K) unsafeAtomicAdd(&ws_cnts[slot * K + tid], lcounts[tid]);
}

__device__ __forceinline__ float block_reduce_256(float v, float* red) {
    v = wave_allreduce_add(v);
    if ((threadIdx.x & 63) == 0) red[threadIdx.x >> 6] = v;
    __syncthreads();
    float total = red[0] + red[1] + red[2] + red[3];
    __syncthreads();
    return total;
}

// Prototype momentum update + renormalize. One block, thread t = column t.
__global__ __launch_bounds__(256) void k_protos(const float* __restrict__ sums_slots,
                                                const float* __restrict__ cnt_slots,
                                                const float* __restrict__ protos_in,
                                                float* __restrict__ protos_out) {
    const int t = threadIdx.x;
    __shared__ float cnts[K];
    __shared__ float red[4];
    if (t < K) {
        float c = 0.0f;
        for (int s = 0; s < NSLOTS; ++s) c += cnt_slots[s * K + t];
        cnts[t] = c;
    }
    __syncthreads();
    for (int k = 0; k < K; ++k) {
        float s = 0.0f;
        for (int sl = 0; sl < NSLOTS; ++sl) s += sums_slots[(size_t)sl * (K * D) + k * D + t];
        float cnt = cnts[k];
        float m = s / fmaxf(cnt, 1.0f);
        float nrm = sqrtf(block_reduce_256(m * m, red));
        float mn = m / fmaxf(nrm, F_EPS);
        float pin = protos_in[k * D + t];
        float upd = (cnt > 0.0f) ? (MOM * pin + (1.0f - MOM) * mn) : pin;
        float nrm2 = sqrtf(block_reduce_256(upd * upd, red));
        protos_out[k * D + t] = upd / fmaxf(nrm2, F_EPS);
    }
}

// Pass 2: mean over rows of (1 - max_k cos(tgt_row, proto_k))
__global__ __launch_bounds__(BT) void k_target(const float* __restrict__ tgt,
                                               const float* __restrict__ protos,
                                               float* __restrict__ loss_slots,
                                               int nrows) {
    const int tid = threadIdx.x;
    const int lane = tid & 63;
    const int gwave = (blockIdx.x * BT + tid) >> 6;
    const int nwaves = gridDim.x * (BT / 64);

    float4 p[K];
#pragma unroll
    for (int k = 0; k < K; ++k)
        p[k] = *(const float4*)(protos + k * D + 4 * lane);

    float acc = 0.0f;
    for (int row = gwave; row < nrows; row += nwaves) {
        float4 v = *(const float4*)(tgt + (size_t)row * D + 4 * lane);
        float nrm = v.x * v.x + v.y * v.y + v.z * v.z + v.w * v.w;
        float dot[K];
#pragma unroll
        for (int k = 0; k < K; ++k)
            dot[k] = v.x * p[k].x + v.y * p[k].y + v.z * p[k].z + v.w * p[k].w;
#pragma unroll
        for (int m = 1; m < 64; m <<= 1) {
            nrm += __shfl_xor(nrm, m, 64);
#pragma unroll
            for (int k = 0; k < K; ++k) dot[k] += __shfl_xor(dot[k], m, 64);
        }
        float inv = 1.0f / fmaxf(sqrtf(nrm), F_EPS);
        float bv = dot[0];
#pragma unroll
        for (int k = 1; k < K; ++k) bv = fmaxf(bv, dot[k]);
        acc += 1.0f - bv * inv;   // all lanes hold the same value
    }
    __shared__ float ls[BT / 64];
    if (lane == 0) ls[tid >> 6] = acc;
    __syncthreads();
    if (tid == 0)
        unsafeAtomicAdd(&loss_slots[blockIdx.x & (NSLOTS - 1)],
                        ls[0] + ls[1] + ls[2] + ls[3]);
}

__global__ void k_loss(const float* __restrict__ loss_slots, float* __restrict__ out, float invN) {
    float v = (threadIdx.x < NSLOTS) ? loss_slots[threadIdx.x] : 0.0f;
    v = wave_allreduce_add(v);
    if (threadIdx.x == 0) out[0] = v * invN;
}

extern "C" void kernel_launch(void* const* d_in, const int* in_sizes, int n_in,
                              void* d_out, int out_size, void* d_ws, size_t ws_size,
                              hipStream_t stream) {
    const float* src = (const float*)d_in[0];
    const float* tgt = (const float*)d_in[1];
    const float* protos = (const float*)d_in[2];
    float* out = (float*)d_out;
    float* ws = (float*)d_ws;

    const int Ns = in_sizes[0] / D;
    const int Nt = in_sizes[1] / D;

    float* ws_sums = ws;                                 // NSLOTS*K*D
    float* ws_cnts = ws_sums + NSLOTS * K * D;           // NSLOTS*K
    float* ws_protos = ws_cnts + NSLOTS * K;             // K*D
    float* ws_loss = ws_protos + K * D;                  // NSLOTS
    const size_t zero_bytes = (size_t)(NSLOTS * K * D + NSLOTS * K + K * D + NSLOTS) * sizeof(float);
    hipMemsetAsync(d_ws, 0, zero_bytes, stream);

    k_source<<<NB, BT, 0, stream>>>(src, protos, ws_sums, ws_cnts, Ns);
    k_protos<<<1, 256, 0, stream>>>(ws_sums, ws_cnts, protos, ws_protos);
    k_target<<<NB, BT, 0, stream>>>(tgt, ws_protos, ws_loss, Nt);
    k_loss<<<1, 64, 0, stream>>>(ws_loss, out, 1.0f / (float)Nt);
}

// Round 2
// 370.576 us; speedup vs baseline: 1.3955x; 1.3955x over previous
//
#include <hip/hip_runtime.h>
#include <math.h>

#define K 8
#define D 256
#define R 64            // rows per tile
#define BT 256          // threads per block
#define GRID 512
#define NSLOT 16
#define F_EPS 1e-12f
#define MOM 0.9f

// LDS arena layout (bytes):
//   tile  : R rows x 264 bf16 (stride 528 B/row)      [0, 33792)
//   part  : [9][4][66] floats                         [33792, 43296)
//   sassign: 64 int                                   [43296, 43552)
//   sinv  : 64 float                                  [43552, 43808)
//   scnt  : 8 float                                   [43808, 43840)
// flush overlay: combine[4][2048] floats (32768 B) reuses tile region.
#define TILE_ROW_BYTES 528
#define PART_OFF 33792
#define SASSIGN_OFF 43296
#define SINV_OFF 43552
#define SCNT_OFF 43808
#define ARENA_BYTES 43840

__device__ __forceinline__ unsigned int pack_bf2(float a, float b) {
    unsigned int ua = __float_as_uint(a), ub = __float_as_uint(b);
    ua = (ua + 0x7fffu + ((ua >> 16) & 1u)) >> 16;          // RNE, low half
    ub = (ub + 0x7fffu + ((ub >> 16) & 1u)) & 0xffff0000u;  // RNE, high half
    return ua | ub;
}
__device__ __forceinline__ float bf_lo(unsigned int d) { return __uint_as_float(d << 16); }
__device__ __forceinline__ float bf_hi(unsigned int d) { return __uint_as_float(d & 0xffff0000u); }

__device__ __forceinline__ float wave_allreduce_add(float v) {
#pragma unroll
    for (int m = 1; m < 64; m <<= 1) v += __shfl_xor(v, m, 64);
    return v;
}

// ---------------- Pass 1: source features -> cluster sums/counts ----------------
__global__ __launch_bounds__(BT, 3) void k_source(const float* __restrict__ src,
                                                  const float* __restrict__ P,
                                                  float* __restrict__ ws_sums,   // [NSLOT][K*D]
                                                  float* __restrict__ ws_cnts,   // [NSLOT][K]
                                                  int nrows) {
    __shared__ __align__(16) unsigned char arena[ARENA_BYTES];
    unsigned char* tileb = arena;
    float* part = (float*)(arena + PART_OFF);
    int* sassign = (int*)(arena + SASSIGN_OFF);
    float* sinv = (float*)(arena + SINV_OFF);
    float* scnt = (float*)(arena + SCNT_OFF);

    const int t = threadIdx.x;
    const int lane = t & 63;
    const int w = t >> 6;
    const int qq = __builtin_amdgcn_readfirstlane(w);   // wave-uniform slice id

    float acc[K][4];
#pragma unroll
    for (int k = 0; k < K; ++k)
#pragma unroll
        for (int j = 0; j < 4; ++j) acc[k][j] = 0.0f;
    if (t < K) scnt[t] = 0.0f;

    const int nTiles = (nrows + R - 1) / R;
    for (int tb = blockIdx.x; tb < nTiles; tb += gridDim.x) {
        const long row0 = (long)tb * R;
        const int rem = nrows - (int)row0;               // >= 1
        const int validElems = (rem >= R) ? (R * D) : (rem * D);
        __syncthreads();  // previous iteration's tile readers done

        // ---- Phase A: global -> bf16 tile ----
        {
            const float* gsrc = src + row0 * D;
#pragma unroll
            for (int it = 0; it < 16; ++it) {
                int e = it * 1024 + t * 4;
                float4 v = make_float4(0.f, 0.f, 0.f, 0.f);
                if (e < validElems) v = *(const float4*)(gsrc + e);
                int r = e >> 8, c = e & 255;
                uint2 pk;
                pk.x = pack_bf2(v.x, v.y);
                pk.y = pack_bf2(v.z, v.w);
                *(uint2*)(tileb + r * TILE_ROW_BYTES + c * 2) = pk;
            }
        }
        __syncthreads();

        // ---- Phase B: partial dots over 64-col slice, all 8 protos + norm ----
        {
            float dot[K];
#pragma unroll
            for (int k = 0; k < K; ++k) dot[k] = 0.0f;
            float nrm = 0.0f;
            const unsigned char* trow = tileb + lane * TILE_ROW_BYTES + qq * 128;
#pragma unroll
            for (int i = 0; i < 8; ++i) {
                uint4 dv = *(const uint4*)(trow + i * 16);
                float x0 = bf_lo(dv.x), x1 = bf_hi(dv.x);
                float x2 = bf_lo(dv.y), x3 = bf_hi(dv.y);
                float x4 = bf_lo(dv.z), x5 = bf_hi(dv.z);
                float x6 = bf_lo(dv.w), x7 = bf_hi(dv.w);
                nrm += x0 * x0 + x1 * x1 + x2 * x2 + x3 * x3
                     + x4 * x4 + x5 * x5 + x6 * x6 + x7 * x7;
#pragma unroll
                for (int k = 0; k < K; ++k) {
                    const float4* pp = (const float4*)(P + k * D + qq * 64 + i * 8);
                    float4 pa = pp[0], pb = pp[1];
                    dot[k] += x0 * pa.x + x1 * pa.y + x2 * pa.z + x3 * pa.w
                            + x4 * pb.x + x5 * pb.y + x6 * pb.z + x7 * pb.w;
                }
            }
#pragma unroll
            for (int k = 0; k < K; ++k) part[k * 264 + qq * 66 + lane] = dot[k];
            part[8 * 264 + qq * 66 + lane] = nrm;
        }
        __syncthreads();

        // ---- Finalize (wave 0): combine slices, argmax, inv-norm ----
        if (w == 0) {
            int r = lane;
            float nr = part[8 * 264 + r] + part[8 * 264 + 66 + r]
                     + part[8 * 264 + 132 + r] + part[8 * 264 + 198 + r];
            float best = -1e30f;
            int bi = 0;
#pragma unroll
            for (int k = 0; k < K; ++k) {
                float dk = part[k * 264 + r] + part[k * 264 + 66 + r]
                         + part[k * 264 + 132 + r] + part[k * 264 + 198 + r];
                if (dk > best) { best = dk; bi = k; }   // first-max semantics
            }
            float inv = 1.0f / fmaxf(sqrtf(nr), F_EPS);
            bool valid = r < rem;
            sassign[r] = bi;
            sinv[r] = valid ? inv : 0.0f;
            if (valid) atomicAdd(&scnt[bi], 1.0f);
        }
        __syncthreads();

        // ---- Scatter: per-wave register accumulation, 16 rows per wave ----
        {
#pragma unroll
            for (int j = 0; j < 16; ++j) {
                int r = w * 16 + j;
                int a = __builtin_amdgcn_readfirstlane(sassign[r]);
                float si = sinv[r];
                uint2 dv = *(const uint2*)(tileb + r * TILE_ROW_BYTES + lane * 8);
                float x0 = bf_lo(dv.x) * si, x1 = bf_hi(dv.x) * si;
                float x2 = bf_lo(dv.y) * si, x3 = bf_hi(dv.y) * si;
                switch (a) {
#define SC_CASE(KK) case KK: acc[KK][0] += x0; acc[KK][1] += x1; acc[KK][2] += x2; acc[KK][3] += x3; break;
                    SC_CASE(0) SC_CASE(1) SC_CASE(2) SC_CASE(3)
                    SC_CASE(4) SC_CASE(5) SC_CASE(6) SC_CASE(7)
#undef SC_CASE
                }
            }
        }
    }

    // ---- Flush: LDS combine across the 4 waves, then global atomics ----
    __syncthreads();               // last tile's scatter done; safe to overlay tile
    float* combine = (float*)arena;
#pragma unroll
    for (int k = 0; k < K; ++k)
        *(float4*)(combine + w * 2048 + k * 256 + lane * 4) =
            make_float4(acc[k][0], acc[k][1], acc[k][2], acc[k][3]);
    __syncthreads();
    const int slot = blockIdx.x & (NSLOT - 1);
    float* gs = ws_sums + (size_t)slot * (K * D);
    for (int i = t; i < K * D; i += BT) {
        float s = combine[i] + combine[2048 + i] + combine[4096 + i] + combine[6144 + i];
        unsafeAtomicAdd(&gs[i], s);
    }
    if (t < K) unsafeAtomicAdd(&ws_cnts[slot * K + t], scnt[t]);
}

// ---------------- Prototype momentum update + renormalize (1 block) ----------------
__device__ __forceinline__ float block_reduce_256(float v, float* red) {
    v = wave_allreduce_add(v);
    if ((threadIdx.x & 63) == 0) red[threadIdx.x >> 6] = v;
    __syncthreads();
    float total = red[0] + red[1] + red[2] + red[3];
    __syncthreads();
    return total;
}

__global__ __launch_bounds__(256) void k_protos(const float* __restrict__ sums_slots,
                                                const float* __restrict__ cnt_slots,
                                                const float* __restrict__ protos_in,
                                                float* __restrict__ protos_out) {
    const int t = threadIdx.x;
    __shared__ float cnts[K];
    __shared__ float red[4];
    if (t < K) {
        float c = 0.0f;
        for (int s = 0; s < NSLOT; ++s) c += cnt_slots[s * K + t];
        cnts[t] = c;
    }
    __syncthreads();
    for (int k = 0; k < K; ++k) {
        float s = 0.0f;
        for (int sl = 0; sl < NSLOT; ++sl) s += sums_slots[(size_t)sl * (K * D) + k * D + t];
        float cnt = cnts[k];
        float m = s / fmaxf(cnt, 1.0f);
        float nrm = sqrtf(block_reduce_256(m * m, red));
        float mn = m / fmaxf(nrm, F_EPS);
        float pin = protos_in[k * D + t];
        float upd = (cnt > 0.0f) ? (MOM * pin + (1.0f - MOM) * mn) : pin;
        float nrm2 = sqrtf(block_reduce_256(upd * upd, red));
        protos_out[k * D + t] = upd / fmaxf(nrm2, F_EPS);
    }
}

// ---------------- Pass 2: target features -> mean(1 - max cos) ----------------
__global__ __launch_bounds__(BT, 3) void k_target(const float* __restrict__ tgt,
                                                  const float* __restrict__ P,
                                                  float* __restrict__ loss_slots,
                                                  int nrows) {
    __shared__ __align__(16) unsigned char arena[ARENA_BYTES];
    unsigned char* tileb = arena;
    float* part = (float*)(arena + PART_OFF);

    const int t = threadIdx.x;
    const int lane = t & 63;
    const int w = t >> 6;
    const int qq = __builtin_amdgcn_readfirstlane(w);

    float lacc = 0.0f;

    const int nTiles = (nrows + R - 1) / R;
    for (int tb = blockIdx.x; tb < nTiles; tb += gridDim.x) {
        const long row0 = (long)tb * R;
        const int rem = nrows - (int)row0;
        const int validElems = (rem >= R) ? (R * D) : (rem * D);
        __syncthreads();

        // Phase A
        {
            const float* gsrc = tgt + row0 * D;
#pragma unroll
            for (int it = 0; it < 16; ++it) {
                int e = it * 1024 + t * 4;
                float4 v = make_float4(0.f, 0.f, 0.f, 0.f);
                if (e < validElems) v = *(const float4*)(gsrc + e);
                int r = e >> 8, c = e & 255;
                uint2 pk;
                pk.x = pack_bf2(v.x, v.y);
                pk.y = pack_bf2(v.z, v.w);
                *(uint2*)(tileb + r * TILE_ROW_BYTES + c * 2) = pk;
            }
        }
        __syncthreads();

        // Phase B
        {
            float dot[K];
#pragma unroll
            for (int k = 0; k < K; ++k) dot[k] = 0.0f;
            float nrm = 0.0f;
            const unsigned char* trow = tileb + lane * TILE_ROW_BYTES + qq * 128;
#pragma unroll
            for (int i = 0; i < 8; ++i) {
                uint4 dv = *(const uint4*)(trow + i * 16);
                float x0 = bf_lo(dv.x), x1 = bf_hi(dv.x);
                float x2 = bf_lo(dv.y), x3 = bf_hi(dv.y);
                float x4 = bf_lo(dv.z), x5 = bf_hi(dv.z);
                float x6 = bf_lo(dv.w), x7 = bf_hi(dv.w);
                nrm += x0 * x0 + x1 * x1 + x2 * x2 + x3 * x3
                     + x4 * x4 + x5 * x5 + x6 * x6 + x7 * x7;
#pragma unroll
                for (int k = 0; k < K; ++k) {
                    const float4* pp = (const float4*)(P + k * D + qq * 64 + i * 8);
                    float4 pa = pp[0], pb = pp[1];
                    dot[k] += x0 * pa.x + x1 * pa.y + x2 * pa.z + x3 * pa.w
                            + x4 * pb.x + x5 * pb.y + x6 * pb.z + x7 * pb.w;
                }
            }
#pragma unroll
            for (int k = 0; k < K; ++k) part[k * 264 + qq * 66 + lane] = dot[k];
            part[8 * 264 + qq * 66 + lane] = nrm;
        }
        __syncthreads();

        // Finalize: loss contribution per row (wave 0)
        if (w == 0) {
            int r = lane;
            float nr = part[8 * 264 + r] + part[8 * 264 + 66 + r]
                     + part[8 * 264 + 132 + r] + part[8 * 264 + 198 + r];
            float best = -1e30f;
#pragma unroll
            for (int k = 0; k < K; ++k) {
                float dk = part[k * 264 + r] + part[k * 264 + 66 + r]
                         + part[k * 264 + 132 + r] + part[k * 264 + 198 + r];
                best = fmaxf(best, dk);
            }
            float inv = 1.0f / fmaxf(sqrtf(nr), F_EPS);
            if (r < rem) lacc += 1.0f - best * inv;
        }
    }

    if (w == 0) {
        float s = wave_allreduce_add(lacc);
        if (lane == 0) unsafeAtomicAdd(&loss_slots[blockIdx.x & (NSLOT - 1)], s);
    }
}

__global__ void k_loss(const float* __restrict__ loss_slots, float* __restrict__ out, float invN) {
    float v = (threadIdx.x < NSLOT) ? loss_slots[threadIdx.x] : 0.0f;
    v = wave_allreduce_add(v);
    if (threadIdx.x == 0) out[0] = v * invN;
}

extern "C" void kernel_launch(void* const* d_in, const int* in_sizes, int n_in,
                              void* d_out, int out_size, void* d_ws, size_t ws_size,
                              hipStream_t stream) {
    const float* src = (const float*)d_in[0];
    const float* tgt = (const float*)d_in[1];
    const float* protos = (const float*)d_in[2];
    float* out = (float*)d_out;
    float* ws = (float*)d_ws;

    const int Ns = in_sizes[0] / D;
    const int Nt = in_sizes[1] / D;

    float* ws_sums = ws;                                 // NSLOT*K*D
    float* ws_cnts = ws_sums + NSLOT * K * D;            // NSLOT*K
    float* ws_protos = ws_cnts + NSLOT * K;              // K*D
    float* ws_loss = ws_protos + K * D;                  // NSLOT
    const size_t zero_bytes = (size_t)(NSLOT * K * D + NSLOT * K + K * D + NSLOT) * sizeof(float);
    hipMemsetAsync(d_ws, 0, zero_bytes, stream);

    k_source<<<GRID, BT, 0, stream>>>(src, protos, ws_sums, ws_cnts, Ns);
    k_protos<<<1, 256, 0, stream>>>(ws_sums, ws_cnts, protos, ws_protos);
    k_target<<<GRID, BT, 0, stream>>>(tgt, ws_protos, ws_loss, Nt);
    k_loss<<<1, 64, 0, stream>>>(ws_loss, out, 1.0f / (float)Nt);
}

// Round 3
// 341.040 us; speedup vs baseline: 1.5163x; 1.0866x over previous
//
#include <hip/hip_runtime.h>
#include <math.h>

#define K 8
#define D 256
#define R 64            // rows per tile
#define BT 256          // threads per block
#define GRID 2048
#define NSLOT 16
#define F_EPS 1e-12f
#define MOM 0.9f

// LDS arena layout (bytes):
//   tile  : R rows x 264 bf16 (stride 528 B/row)      [0, 33792)
//   part  : [9][4][66] floats                         [33792, 43296)
//   sassign: 64 int                                   [43296, 43552)
//   sinv  : 64 float                                  [43552, 43808)
//   scnt  : 8 float (+pad)                            [43808, 43840)
//   protos: K*D floats (8 KB)                         [43840, 52032)
// flush overlay: combine[4][2048] floats (32768 B) reuses tile region.
#define TILE_ROW_BYTES 528
#define PART_OFF 33792
#define SASSIGN_OFF 43296
#define SINV_OFF 43552
#define SCNT_OFF 43808
#define PROTO_OFF 43840
#define ARENA_BYTES 52032

__device__ __forceinline__ unsigned int pack_bf2(float a, float b) {
    unsigned int ua = __float_as_uint(a), ub = __float_as_uint(b);
    ua = (ua + 0x7fffu + ((ua >> 16) & 1u)) >> 16;          // RNE, low half
    ub = (ub + 0x7fffu + ((ub >> 16) & 1u)) & 0xffff0000u;  // RNE, high half
    return ua | ub;
}
__device__ __forceinline__ float bf_lo(unsigned int d) { return __uint_as_float(d << 16); }
__device__ __forceinline__ float bf_hi(unsigned int d) { return __uint_as_float(d & 0xffff0000u); }

__device__ __forceinline__ float wave_allreduce_add(float v) {
#pragma unroll
    for (int m = 1; m < 64; m <<= 1) v += __shfl_xor(v, m, 64);
    return v;
}

// ---------------- Pass 1: source features -> cluster sums/counts ----------------
__global__ __launch_bounds__(BT, 3) void k_source(const float* __restrict__ src,
                                                  const float* __restrict__ P,
                                                  float* __restrict__ ws_sums,   // [NSLOT][K*D]
                                                  float* __restrict__ ws_cnts,   // [NSLOT][K]
                                                  int nrows) {
    __shared__ __align__(16) unsigned char arena[ARENA_BYTES];
    unsigned char* tileb = arena;
    float* part = (float*)(arena + PART_OFF);
    int* sassign = (int*)(arena + SASSIGN_OFF);
    float* sinv = (float*)(arena + SINV_OFF);
    float* scnt = (float*)(arena + SCNT_OFF);
    float* pROT = (float*)(arena + PROTO_OFF);

    const int t = threadIdx.x;
    const int lane = t & 63;
    const int w = t >> 6;
    const int qq = __builtin_amdgcn_readfirstlane(w);   // wave-uniform slice id

    // stage prototypes into LDS (once per block)
#pragma unroll
    for (int i = 0; i < 2; ++i) {
        int e = (t + i * BT) * 4;
        *(float4*)(pROT + e) = *(const float4*)(P + e);
    }

    float acc[K][4];
#pragma unroll
    for (int k = 0; k < K; ++k)
#pragma unroll
        for (int j = 0; j < 4; ++j) acc[k][j] = 0.0f;
    if (t < K) scnt[t] = 0.0f;

    const int nTiles = (nrows + R - 1) / R;
    for (int tb = blockIdx.x; tb < nTiles; tb += gridDim.x) {
        const long row0 = (long)tb * R;
        const int rem = nrows - (int)row0;               // >= 1
        const int validElems = (rem >= R) ? (R * D) : (rem * D);
        __syncthreads();  // previous iteration's tile readers done; protos visible

        // ---- Phase A: global -> bf16 tile ----
        {
            const float* gsrc = src + row0 * D;
#pragma unroll
            for (int it = 0; it < 16; ++it) {
                int e = it * 1024 + t * 4;
                float4 v = make_float4(0.f, 0.f, 0.f, 0.f);
                if (e < validElems) v = *(const float4*)(gsrc + e);
                int r = e >> 8, c = e & 255;
                uint2 pk;
                pk.x = pack_bf2(v.x, v.y);
                pk.y = pack_bf2(v.z, v.w);
                *(uint2*)(tileb + r * TILE_ROW_BYTES + c * 2) = pk;
            }
        }
        __syncthreads();

        // ---- Phase B: partial dots over 64-col slice, all 8 protos + norm ----
        {
            float dot[K];
#pragma unroll
            for (int k = 0; k < K; ++k) dot[k] = 0.0f;
            float nrm = 0.0f;
            const unsigned char* trow = tileb + lane * TILE_ROW_BYTES + qq * 128;
#pragma unroll
            for (int i = 0; i < 8; ++i) {
                uint4 dv = *(const uint4*)(trow + i * 16);
                float x0 = bf_lo(dv.x), x1 = bf_hi(dv.x);
                float x2 = bf_lo(dv.y), x3 = bf_hi(dv.y);
                float x4 = bf_lo(dv.z), x5 = bf_hi(dv.z);
                float x6 = bf_lo(dv.w), x7 = bf_hi(dv.w);
                nrm += x0 * x0 + x1 * x1 + x2 * x2 + x3 * x3
                     + x4 * x4 + x5 * x5 + x6 * x6 + x7 * x7;
#pragma unroll
                for (int k = 0; k < K; ++k) {
                    const float4* pp = (const float4*)(pROT + k * D + qq * 64 + i * 8);
                    float4 pa = pp[0], pb = pp[1];   // wave-uniform LDS broadcast
                    dot[k] += x0 * pa.x + x1 * pa.y + x2 * pa.z + x3 * pa.w
                            + x4 * pb.x + x5 * pb.y + x6 * pb.z + x7 * pb.w;
                }
            }
#pragma unroll
            for (int k = 0; k < K; ++k) part[k * 264 + qq * 66 + lane] = dot[k];
            part[8 * 264 + qq * 66 + lane] = nrm;
        }
        __syncthreads();

        // ---- Finalize (wave 0): combine slices, argmax, inv-norm ----
        if (w == 0) {
            int r = lane;
            float nr = part[8 * 264 + r] + part[8 * 264 + 66 + r]
                     + part[8 * 264 + 132 + r] + part[8 * 264 + 198 + r];
            float best = -1e30f;
            int bi = 0;
#pragma unroll
            for (int k = 0; k < K; ++k) {
                float dk = part[k * 264 + r] + part[k * 264 + 66 + r]
                         + part[k * 264 + 132 + r] + part[k * 264 + 198 + r];
                if (dk > best) { best = dk; bi = k; }   // first-max semantics
            }
            float inv = 1.0f / fmaxf(sqrtf(nr), F_EPS);
            bool valid = r < rem;
            sassign[r] = bi;
            sinv[r] = valid ? inv : 0.0f;
            if (valid) atomicAdd(&scnt[bi], 1.0f);
        }
        __syncthreads();

        // ---- Scatter: per-wave register accumulation, 16 rows per wave ----
        {
#pragma unroll
            for (int j = 0; j < 16; ++j) {
                int r = w * 16 + j;
                int a = __builtin_amdgcn_readfirstlane(sassign[r]);
                float si = sinv[r];
                uint2 dv = *(const uint2*)(tileb + r * TILE_ROW_BYTES + lane * 8);
                float x0 = bf_lo(dv.x) * si, x1 = bf_hi(dv.x) * si;
                float x2 = bf_lo(dv.y) * si, x3 = bf_hi(dv.y) * si;
                switch (a) {
#define SC_CASE(KK) case KK: acc[KK][0] += x0; acc[KK][1] += x1; acc[KK][2] += x2; acc[KK][3] += x3; break;
                    SC_CASE(0) SC_CASE(1) SC_CASE(2) SC_CASE(3)
                    SC_CASE(4) SC_CASE(5) SC_CASE(6) SC_CASE(7)
#undef SC_CASE
                }
            }
        }
    }

    // ---- Flush: LDS combine across the 4 waves, then global atomics ----
    __syncthreads();               // last tile's scatter done; safe to overlay tile
    float* combine = (float*)arena;
#pragma unroll
    for (int k = 0; k < K; ++k)
        *(float4*)(combine + w * 2048 + k * 256 + lane * 4) =
            make_float4(acc[k][0], acc[k][1], acc[k][2], acc[k][3]);
    __syncthreads();
    const int slot = blockIdx.x & (NSLOT - 1);
    float* gs = ws_sums + (size_t)slot * (K * D);
    for (int i = t; i < K * D; i += BT) {
        float s = combine[i] + combine[2048 + i] + combine[4096 + i] + combine[6144 + i];
        unsafeAtomicAdd(&gs[i], s);
    }
    if (t < K) unsafeAtomicAdd(&ws_cnts[slot * K + t], scnt[t]);
}

// ---------------- Prototype momentum update + renormalize (1 block) ----------------
__device__ __forceinline__ float block_reduce_256(float v, float* red) {
    v = wave_allreduce_add(v);
    if ((threadIdx.x & 63) == 0) red[threadIdx.x >> 6] = v;
    __syncthreads();
    float total = red[0] + red[1] + red[2] + red[3];
    __syncthreads();
    return total;
}

__global__ __launch_bounds__(256) void k_protos(const float* __restrict__ sums_slots,
                                                const float* __restrict__ cnt_slots,
                                                const float* __restrict__ protos_in,
                                                float* __restrict__ protos_out) {
    const int t = threadIdx.x;
    __shared__ float cnts[K];
    __shared__ float red[4];
    if (t < K) {
        float c = 0.0f;
        for (int s = 0; s < NSLOT; ++s) c += cnt_slots[s * K + t];
        cnts[t] = c;
    }
    __syncthreads();
    for (int k = 0; k < K; ++k) {
        float s = 0.0f;
        for (int sl = 0; sl < NSLOT; ++sl) s += sums_slots[(size_t)sl * (K * D) + k * D + t];
        float cnt = cnts[k];
        float m = s / fmaxf(cnt, 1.0f);
        float nrm = sqrtf(block_reduce_256(m * m, red));
        float mn = m / fmaxf(nrm, F_EPS);
        float pin = protos_in[k * D + t];
        float upd = (cnt > 0.0f) ? (MOM * pin + (1.0f - MOM) * mn) : pin;
        float nrm2 = sqrtf(block_reduce_256(upd * upd, red));
        protos_out[k * D + t] = upd / fmaxf(nrm2, F_EPS);
    }
}

// ---------------- Pass 2: target features -> mean(1 - max cos) ----------------
__global__ __launch_bounds__(BT, 3) void k_target(const float* __restrict__ tgt,
                                                  const float* __restrict__ P,
                                                  float* __restrict__ loss_slots,
                                                  int nrows) {
    __shared__ __align__(16) unsigned char arena[ARENA_BYTES];
    unsigned char* tileb = arena;
    float* part = (float*)(arena + PART_OFF);
    float* pROT = (float*)(arena + PROTO_OFF);

    const int t = threadIdx.x;
    const int lane = t & 63;
    const int w = t >> 6;
    const int qq = __builtin_amdgcn_readfirstlane(w);

#pragma unroll
    for (int i = 0; i < 2; ++i) {
        int e = (t + i * BT) * 4;
        *(float4*)(pROT + e) = *(const float4*)(P + e);
    }

    float lacc = 0.0f;

    const int nTiles = (nrows + R - 1) / R;
    for (int tb = blockIdx.x; tb < nTiles; tb += gridDim.x) {
        const long row0 = (long)tb * R;
        const int rem = nrows - (int)row0;
        const int validElems = (rem >= R) ? (R * D) : (rem * D);
        __syncthreads();

        // Phase A
        {
            const float* gsrc = tgt + row0 * D;
#pragma unroll
            for (int it = 0; it < 16; ++it) {
                int e = it * 1024 + t * 4;
                float4 v = make_float4(0.f, 0.f, 0.f, 0.f);
                if (e < validElems) v = *(const float4*)(gsrc + e);
                int r = e >> 8, c = e & 255;
                uint2 pk;
                pk.x = pack_bf2(v.x, v.y);
                pk.y = pack_bf2(v.z, v.w);
                *(uint2*)(tileb + r * TILE_ROW_BYTES + c * 2) = pk;
            }
        }
        __syncthreads();

        // Phase B
        {
            float dot[K];
#pragma unroll
            for (int k = 0; k < K; ++k) dot[k] = 0.0f;
            float nrm = 0.0f;
            const unsigned char* trow = tileb + lane * TILE_ROW_BYTES + qq * 128;
#pragma unroll
            for (int i = 0; i < 8; ++i) {
                uint4 dv = *(const uint4*)(trow + i * 16);
                float x0 = bf_lo(dv.x), x1 = bf_hi(dv.x);
                float x2 = bf_lo(dv.y), x3 = bf_hi(dv.y);
                float x4 = bf_lo(dv.z), x5 = bf_hi(dv.z);
                float x6 = bf_lo(dv.w), x7 = bf_hi(dv.w);
                nrm += x0 * x0 + x1 * x1 + x2 * x2 + x3 * x3
                     + x4 * x4 + x5 * x5 + x6 * x6 + x7 * x7;
#pragma unroll
                for (int k = 0; k < K; ++k) {
                    const float4* pp = (const float4*)(pROT + k * D + qq * 64 + i * 8);
                    float4 pa = pp[0], pb = pp[1];
                    dot[k] += x0 * pa.x + x1 * pa.y + x2 * pa.z + x3 * pa.w
                            + x4 * pb.x + x5 * pb.y + x6 * pb.z + x7 * pb.w;
                }
            }
#pragma unroll
            for (int k = 0; k < K; ++k) part[k * 264 + qq * 66 + lane] = dot[k];
            part[8 * 264 + qq * 66 + lane] = nrm;
        }
        __syncthreads();

        // Finalize: loss contribution per row (wave 0)
        if (w == 0) {
            int r = lane;
            float nr = part[8 * 264 + r] + part[8 * 264 + 66 + r]
                     + part[8 * 264 + 132 + r] + part[8 * 264 + 198 + r];
            float best = -1e30f;
#pragma unroll
            for (int k = 0; k < K; ++k) {
                float dk = part[k * 264 + r] + part[k * 264 + 66 + r]
                         + part[k * 264 + 132 + r] + part[k * 264 + 198 + r];
                best = fmaxf(best, dk);
            }
            float inv = 1.0f / fmaxf(sqrtf(nr), F_EPS);
            if (r < rem) lacc += 1.0f - best * inv;
        }
    }

    if (w == 0) {
        float s = wave_allreduce_add(lacc);
        if (lane == 0) unsafeAtomicAdd(&loss_slots[blockIdx.x & (NSLOT - 1)], s);
    }
}

__global__ void k_loss(const float* __restrict__ loss_slots, float* __restrict__ out, float invN) {
    float v = (threadIdx.x < NSLOT) ? loss_slots[threadIdx.x] : 0.0f;
    v = wave_allreduce_add(v);
    if (threadIdx.x == 0) out[0] = v * invN;
}

extern "C" void kernel_launch(void* const* d_in, const int* in_sizes, int n_in,
                              void* d_out, int out_size, void* d_ws, size_t ws_size,
                              hipStream_t stream) {
    const float* src = (const float*)d_in[0];
    const float* tgt = (const float*)d_in[1];
    const float* protos = (const float*)d_in[2];
    float* out = (float*)d_out;
    float* ws = (float*)d_ws;

    const int Ns = in_sizes[0] / D;
    const int Nt = in_sizes[1] / D;

    float* ws_sums = ws;                                 // NSLOT*K*D
    float* ws_cnts = ws_sums + NSLOT * K * D;            // NSLOT*K
    float* ws_protos = ws_cnts + NSLOT * K;              // K*D
    float* ws_loss = ws_protos + K * D;                  // NSLOT
    const size_t zero_bytes = (size_t)(NSLOT * K * D + NSLOT * K + K * D + NSLOT) * sizeof(float);
    hipMemsetAsync(d_ws, 0, zero_bytes, stream);

    const int nTilesS = (Ns + R - 1) / R;
    const int nTilesT = (Nt + R - 1) / R;
    const int gridS = (nTilesS < GRID) ? nTilesS : GRID;
    const int gridT = (nTilesT < GRID) ? nTilesT : GRID;

    k_source<<<gridS, BT, 0, stream>>>(src, protos, ws_sums, ws_cnts, Ns);
    k_protos<<<1, 256, 0, stream>>>(ws_sums, ws_cnts, protos, ws_protos);
    k_target<<<gridT, BT, 0, stream>>>(tgt, ws_protos, ws_loss, Nt);
    k_loss<<<1, 64, 0, stream>>>(ws_loss, out, 1.0f / (float)Nt);
}

// Round 4
// 327.822 us; speedup vs baseline: 1.5775x; 1.0403x over previous
//
#include <hip/hip_runtime.h>
#include <math.h>

#define K 8
#define D 256
#define R 64
#define BT 256
#define GRID 512
#define NSLOT 16
#define F_EPS 1e-12f
#define MOM 0.9f

typedef __attribute__((ext_vector_type(8))) short short8;
typedef __attribute__((ext_vector_type(4))) float f32x4;

#define WROW 528                    // bytes per LDS tile row (264 bf16, pad -> conflict-free)
#define WTILE (16 * WROW)           // per-wave private tile region: 8448 B
#define SCNT_OFF (4 * WTILE)        // 33792
#define ARENA_BYTES (SCNT_OFF + 32)

__device__ __forceinline__ unsigned int pack_bf2(float a, float b) {
    unsigned int ua = __float_as_uint(a), ub = __float_as_uint(b);
    ua = (ua + 0x7fffu + ((ua >> 16) & 1u)) >> 16;          // RNE, low half
    ub = (ub + 0x7fffu + ((ub >> 16) & 1u)) & 0xffff0000u;  // RNE, high half
    return ua | ub;
}
__device__ __forceinline__ float bf_lo(unsigned int d) { return __uint_as_float(d << 16); }
__device__ __forceinline__ float bf_hi(unsigned int d) { return __uint_as_float(d & 0xffff0000u); }

__device__ __forceinline__ float wave_allreduce_add(float v) {
#pragma unroll
    for (int m = 1; m < 64; m <<= 1) v += __shfl_xor(v, m, 64);
    return v;
}
__device__ __forceinline__ float readlane_f(float v, int l) {
    return __int_as_float(__builtin_amdgcn_readlane(__float_as_int(v), l));
}

// Load proto B-fragments for mfma_f32_16x16x32_bf16.
// B[k_local = (lane>>4)*8 + j][n = lane&15] ; B[k][n] = P[n][k_global]
__device__ __forceinline__ void load_bfrags(const float* __restrict__ P, int mrow, int sl,
                                            short8* bfrag) {
    const bool pv = mrow < K;
    const float* pb = P + mrow * D + sl * 8;
#pragma unroll
    for (int c = 0; c < 8; ++c) {
        float4 a = make_float4(0.f, 0.f, 0.f, 0.f), b = a;
        if (pv) {
            a = *(const float4*)(pb + c * 32);
            b = *(const float4*)(pb + c * 32 + 4);
        }
        union { unsigned int u[4]; short8 s; } f;
        f.u[0] = pack_bf2(a.x, a.y); f.u[1] = pack_bf2(a.z, a.w);
        f.u[2] = pack_bf2(b.x, b.y); f.u[3] = pack_bf2(b.z, b.w);
        bfrag[c] = f.s;
    }
}

// ---------------- Pass 1: source features -> cluster sums/counts ----------------
__global__ __launch_bounds__(BT) void k_source(const float* __restrict__ src,
                                               const float* __restrict__ P,
                                               float* __restrict__ ws_sums,   // [NSLOT][K*D]
                                               float* __restrict__ ws_cnts,   // [NSLOT][K]
                                               int nrows) {
    __shared__ __align__(16) unsigned char arena[ARENA_BYTES];
    float* scnt = (float*)(arena + SCNT_OFF);

    const int t = threadIdx.x;
    const int lane = t & 63;
    const int w = t >> 6;
    const int mrow = lane & 15;     // row within this wave's 16-row strip
    const int sl = lane >> 4;       // k-slice quarter
    unsigned char* mytile = arena + w * WTILE;

    if (t < K) scnt[t] = 0.0f;

    short8 bfrag[8];
    load_bfrags(P, mrow, sl, bfrag);

    float acc[K][4];
    float cnta[K];
#pragma unroll
    for (int k = 0; k < K; ++k) {
        cnta[k] = 0.0f;
#pragma unroll
        for (int j = 0; j < 4; ++j) acc[k][j] = 0.0f;
    }

    const int nTiles = (nrows + R - 1) / R;
    for (int tb = blockIdx.x; tb < nTiles; tb += gridDim.x) {
        const int rbase = tb * R + w * 16;
        const int grow = rbase + mrow;
        const bool valid = grow < nrows;
        const float* rp = src + (size_t)grow * D + sl * 8;

        f32x4 dacc = {0.f, 0.f, 0.f, 0.f};
        float nrm = 0.0f;
#pragma unroll
        for (int c = 0; c < 8; ++c) {
            float4 a = make_float4(0.f, 0.f, 0.f, 0.f), b = a;
            if (valid) {
                a = *(const float4*)(rp + c * 32);
                b = *(const float4*)(rp + c * 32 + 4);
            }
            nrm += a.x * a.x + a.y * a.y + a.z * a.z + a.w * a.w
                 + b.x * b.x + b.y * b.y + b.z * b.z + b.w * b.w;
            union { unsigned int u[4]; short8 s; uint4 q; } f;
            f.u[0] = pack_bf2(a.x, a.y); f.u[1] = pack_bf2(a.z, a.w);
            f.u[2] = pack_bf2(b.x, b.y); f.u[3] = pack_bf2(b.z, b.w);
            *(uint4*)(mytile + mrow * WROW + c * 64 + sl * 16) = f.q;   // A-layout row store
            dacc = __builtin_amdgcn_mfma_f32_16x16x32_bf16(f.s, bfrag[c], dacc, 0, 0, 0);
        }
        nrm += __shfl_xor(nrm, 16, 64);
        nrm += __shfl_xor(nrm, 32, 64);
        const float inv = 1.0f / fmaxf(sqrtf(nrm), F_EPS);

        // argmax over protos: dots at D[row=(lane>>4)*4+reg][proto=lane&15]
        float bv[4]; int bi[4];
#pragma unroll
        for (int j = 0; j < 4; ++j) { bv[j] = (mrow < K) ? dacc[j] : -1e30f; bi[j] = mrow; }
#pragma unroll
        for (int m = 1; m <= 4; m <<= 1) {
#pragma unroll
            for (int j = 0; j < 4; ++j) {
                float ov = __shfl_xor(bv[j], m, 64);
                int oi = __shfl_xor(bi[j], m, 64);
                if (ov > bv[j] || (ov == bv[j] && oi < bi[j])) { bv[j] = ov; bi[j] = oi; }
            }
        }

        // scatter this wave's 16 rows (reads the LDS it just wrote; same-wave, no barrier)
#pragma unroll
        for (int j = 0; j < 16; ++j) {
            if (rbase + j >= nrows) break;                         // uniform
            const int a = __builtin_amdgcn_readlane(bi[j & 3], (j >> 2) * 16);
            const float iv = readlane_f(inv, j);
            uint2 dv = *(const uint2*)(mytile + j * WROW + lane * 8);
            float x0 = bf_lo(dv.x) * iv, x1 = bf_hi(dv.x) * iv;
            float x2 = bf_lo(dv.y) * iv, x3 = bf_hi(dv.y) * iv;
            switch (a) {
#define SC_CASE(KK) case KK: acc[KK][0] += x0; acc[KK][1] += x1; acc[KK][2] += x2; acc[KK][3] += x3; cnta[KK] += 1.0f; break;
                SC_CASE(0) SC_CASE(1) SC_CASE(2) SC_CASE(3)
                SC_CASE(4) SC_CASE(5) SC_CASE(6) SC_CASE(7)
#undef SC_CASE
            }
        }
    }

    // ---- Flush: combine 4 waves in LDS (overlay tile), then global atomics ----
    __syncthreads();
    float* combine = (float*)arena;   // 32 KB overlay
#pragma unroll
    for (int k = 0; k < K; ++k)
        *(float4*)(combine + w * 2048 + k * 256 + lane * 4) =
            make_float4(acc[k][0], acc[k][1], acc[k][2], acc[k][3]);
    if (lane == 0) {
#pragma unroll
        for (int k = 0; k < K; ++k) atomicAdd(&scnt[k], cnta[k]);
    }
    __syncthreads();
    const int slot = blockIdx.x & (NSLOT - 1);
    float* gs = ws_sums + (size_t)slot * (K * D);
    for (int i = t; i < K * D; i += BT) {
        float s = combine[i] + combine[2048 + i] + combine[4096 + i] + combine[6144 + i];
        unsafeAtomicAdd(&gs[i], s);
    }
    if (t < K) unsafeAtomicAdd(&ws_cnts[slot * K + t], scnt[t]);
}

// ---------------- Prototype momentum update + renormalize (1 block, wave per proto) ----------------
__global__ __launch_bounds__(512) void k_protos(const float* __restrict__ sums_slots,
                                                const float* __restrict__ cnt_slots,
                                                const float* __restrict__ protos_in,
                                                float* __restrict__ protos_out) {
    const int t = threadIdx.x;
    const int k = t >> 6;
    const int lane = t & 63;

    float c = 0.0f;
    for (int s = 0; s < NSLOT; ++s) c += cnt_slots[s * K + k];

    float4 sm = make_float4(0.f, 0.f, 0.f, 0.f);
    for (int s = 0; s < NSLOT; ++s) {
        float4 v = *(const float4*)(sums_slots + (size_t)s * (K * D) + k * D + lane * 4);
        sm.x += v.x; sm.y += v.y; sm.z += v.z; sm.w += v.w;
    }
    const float cc = fmaxf(c, 1.0f);
    float4 m = make_float4(sm.x / cc, sm.y / cc, sm.z / cc, sm.w / cc);
    float nr = wave_allreduce_add(m.x * m.x + m.y * m.y + m.z * m.z + m.w * m.w);
    const float s1 = 1.0f / fmaxf(sqrtf(nr), F_EPS);
    float4 pin = *(const float4*)(protos_in + k * D + lane * 4);
    float4 upd;
    if (c > 0.0f) {
        upd = make_float4(MOM * pin.x + (1.0f - MOM) * m.x * s1,
                          MOM * pin.y + (1.0f - MOM) * m.y * s1,
                          MOM * pin.z + (1.0f - MOM) * m.z * s1,
                          MOM * pin.w + (1.0f - MOM) * m.w * s1);
    } else {
        upd = pin;
    }
    float n2 = wave_allreduce_add(upd.x * upd.x + upd.y * upd.y + upd.z * upd.z + upd.w * upd.w);
    const float s2 = 1.0f / fmaxf(sqrtf(n2), F_EPS);
    *(float4*)(protos_out + k * D + lane * 4) =
        make_float4(upd.x * s2, upd.y * s2, upd.z * s2, upd.w * s2);
}

// ---------------- Pass 2: target features -> mean(1 - max cos) ----------------
__global__ __launch_bounds__(BT) void k_target(const float* __restrict__ tgt,
                                               const float* __restrict__ P,
                                               float* __restrict__ loss_slots,
                                               int nrows) {
    const int t = threadIdx.x;
    const int lane = t & 63;
    const int w = t >> 6;
    const int mrow = lane & 15;
    const int sl = lane >> 4;

    short8 bfrag[8];
    load_bfrags(P, mrow, sl, bfrag);

    float lacc = 0.0f;

    const int nTiles = (nrows + R - 1) / R;
    for (int tb = blockIdx.x; tb < nTiles; tb += gridDim.x) {
        const int rbase = tb * R + w * 16;
        const int grow = rbase + mrow;
        const bool valid = grow < nrows;
        const float* rp = tgt + (size_t)grow * D + sl * 8;

        f32x4 dacc = {0.f, 0.f, 0.f, 0.f};
        float nrm = 0.0f;
#pragma unroll
        for (int c = 0; c < 8; ++c) {
            float4 a = make_float4(0.f, 0.f, 0.f, 0.f), b = a;
            if (valid) {
                a = *(const float4*)(rp + c * 32);
                b = *(const float4*)(rp + c * 32 + 4);
            }
            nrm += a.x * a.x + a.y * a.y + a.z * a.z + a.w * a.w
                 + b.x * b.x + b.y * b.y + b.z * b.z + b.w * b.w;
            union { unsigned int u[4]; short8 s; } f;
            f.u[0] = pack_bf2(a.x, a.y); f.u[1] = pack_bf2(a.z, a.w);
            f.u[2] = pack_bf2(b.x, b.y); f.u[3] = pack_bf2(b.z, b.w);
            dacc = __builtin_amdgcn_mfma_f32_16x16x32_bf16(f.s, bfrag[c], dacc, 0, 0, 0);
        }
        nrm += __shfl_xor(nrm, 16, 64);
        nrm += __shfl_xor(nrm, 32, 64);
        const float inv = 1.0f / fmaxf(sqrtf(nrm), F_EPS);

        float mx[4];
#pragma unroll
        for (int j = 0; j < 4; ++j) mx[j] = (mrow < K) ? dacc[j] : -1e30f;
#pragma unroll
        for (int m = 1; m <= 4; m <<= 1) {
#pragma unroll
            for (int j = 0; j < 4; ++j) mx[j] = fmaxf(mx[j], __shfl_xor(mx[j], m, 64));
        }

#pragma unroll
        for (int j = 0; j < 16; ++j) {
            if (rbase + j >= nrows) break;                         // uniform
            const float bd = readlane_f(mx[j & 3], (j >> 2) * 16);
            const float iv = readlane_f(inv, j);
            lacc += 1.0f - bd * iv;                                // wave-uniform
        }
    }

    if (lane == 0)
        unsafeAtomicAdd(&loss_slots[blockIdx.x & (NSLOT - 1)], lacc);
}

__global__ void k_loss(const float* __restrict__ loss_slots, float* __restrict__ out, float invN) {
    float v = (threadIdx.x < NSLOT) ? loss_slots[threadIdx.x] : 0.0f;
    v = wave_allreduce_add(v);
    if (threadIdx.x == 0) out[0] = v * invN;
}

extern "C" void kernel_launch(void* const* d_in, const int* in_sizes, int n_in,
                              void* d_out, int out_size, void* d_ws, size_t ws_size,
                              hipStream_t stream) {
    const float* src = (const float*)d_in[0];
    const float* tgt = (const float*)d_in[1];
    const float* protos = (const float*)d_in[2];
    float* out = (float*)d_out;
    float* ws = (float*)d_ws;

    const int Ns = in_sizes[0] / D;
    const int Nt = in_sizes[1] / D;

    float* ws_sums = ws;                                 // NSLOT*K*D
    float* ws_cnts = ws_sums + NSLOT * K * D;            // NSLOT*K
    float* ws_loss = ws_cnts + NSLOT * K;                // NSLOT
    float* ws_protos = ws_loss + NSLOT;                  // K*D (no zero-init needed)
    const size_t zero_bytes = (size_t)(NSLOT * K * D + NSLOT * K + NSLOT) * sizeof(float);
    hipMemsetAsync(d_ws, 0, zero_bytes, stream);

    const int nTilesS = (Ns + R - 1) / R;
    const int nTilesT = (Nt + R - 1) / R;
    const int gridS = (nTilesS < GRID) ? nTilesS : GRID;
    const int gridT = (nTilesT < GRID) ? nTilesT : GRID;

    k_source<<<gridS, BT, 0, stream>>>(src, protos, ws_sums, ws_cnts, Ns);
    k_protos<<<1, 512, 0, stream>>>(ws_sums, ws_cnts, protos, ws_protos);
    k_target<<<gridT, BT, 0, stream>>>(tgt, ws_protos, ws_loss, Nt);
    k_loss<<<1, 64, 0, stream>>>(ws_loss, out, 1.0f / (float)Nt);
}